// Round 5
// baseline (233.683 us; speedup 1.0000x reference)
//
#include <hip/hip_runtime.h>
#include <hip/hip_fp16.h>

#define H 256
#define W 512
#define HW (H*W)
#define NPIXF 524288.0f
#define SPAN 11
#define KK 23
#define NBINS (KK*KK)   // 529

#define LOG2E 1.4426950408889634f
#define CEXP  (-0.7213475204444817f)   // -0.5*log2(e)
#define CIND  (CEXP/36.0f)             // 1/SIG_XY^2
// sqrt(|CEXP|*100) and sqrt(|CEXP|*25): fold rgb/depth sigma scaling into staged f16 data
#define KRGB  8.4932180f
#define KDEP  4.2466090f

// tile geometry: center 32 cols x 16 rows per block, halo +11 rows below, +-11 cols
#define TX 32
#define TYR 16
#define TROWS 27          // TYR + 11
#define TCOLS 54          // TX + 22
#define TPIX (TROWS*TCOLS) // 1458

#define NCRF 1024         // 16x16x4 crf blocks
#define NSTAT 44
#define NBLK (NCRF + NSTAT)

typedef _Float16 h2 __attribute__((ext_vector_type(2)));

struct alignas(16) PixV { h2 rg, bd, y01, y2m; };   // 16 B staged pixel (rgb,d pre-scaled)

__device__ __forceinline__ h2 pack2(float a, float b) {
  h2 r; r.x = (_Float16)a; r.y = (_Float16)b; return r;
}

__device__ __forceinline__ float agent_load(const float* p) {
  return __hip_atomic_load(p, __ATOMIC_RELAXED, __HIP_MEMORY_SCOPE_AGENT);
}

// 64-lane sum on the VALU pipe (DPP). Total lands in lane 63.
__device__ __forceinline__ float dpp_sum(float x) {
  x += __int_as_float(__builtin_amdgcn_update_dpp(0, __float_as_int(x), 0x111, 0xf, 0xf, true)); // row_shr:1
  x += __int_as_float(__builtin_amdgcn_update_dpp(0, __float_as_int(x), 0x112, 0xf, 0xf, true)); // row_shr:2
  x += __int_as_float(__builtin_amdgcn_update_dpp(0, __float_as_int(x), 0x114, 0xf, 0xf, true)); // row_shr:4
  x += __int_as_float(__builtin_amdgcn_update_dpp(0, __float_as_int(x), 0x118, 0xf, 0xf, true)); // row_shr:8
  x += __int_as_float(__builtin_amdgcn_update_dpp(0, __float_as_int(x), 0x142, 0xa, 0xf, true)); // row_bcast:15
  x += __int_as_float(__builtin_amdgcn_update_dpp(0, __float_as_int(x), 0x143, 0xc, 0xf, true)); // row_bcast:31
  return x;
}

__device__ __forceinline__ float wave_sum(float x) {
  #pragma unroll
  for (int s = 1; s < 64; s <<= 1) x += __shfl_xor(x, s, 64);
  return x;
}

// pair compatibility: kv(a1,a2) * (1 - <yC, yN>), all f16-packed inputs
__device__ __forceinline__ float paircc(const PixV& C, const PixV& N,
                                        h2 nc01, h2 nc2z, float lind) {
  h2 drg = N.rg - C.rg;            // v_pk_add_f16 (neg)
  h2 dbd = N.bd - C.bd;
  float dbf = (float)dbd.x;
  float ddf = (float)dbd.y;
#if __has_builtin(__builtin_amdgcn_fdot2)
  float q  = __builtin_amdgcn_fdot2(drg, drg, dbf*dbf, false);   // dr^2+dg^2+db^2 (scaled)
  float a1 = lind - q;
  float w1 = __builtin_amdgcn_fdot2(N.y01, nc01, 1.0f, false);   // 1 - y0Y0 - y1Y1
  float w  = __builtin_amdgcn_fdot2(N.y2m, nc2z, w1, false);     // ... - y2Y2 (m lane masked by 0)
#else
  float dr = (float)drg.x, dg = (float)drg.y;
  float a1 = fmaf(-dr, dr, fmaf(-dg, dg, fmaf(-dbf, dbf, lind)));
  float ny0 = (float)N.y01.x, ny1 = (float)N.y01.y, ny2 = (float)N.y2m.x;
  float cy0 = (float)C.y01.x, cy1 = (float)C.y01.y, cy2 = (float)C.y2m.x;
  float w  = fmaf(-ny0, cy0, fmaf(-ny1, cy1, fmaf(-ny2, cy2, 1.0f)));
  (void)nc01; (void)nc2z;
#endif
  float a2 = -(ddf*ddf);
  float kv = __builtin_amdgcn_exp2f(a1) + __builtin_amdgcn_exp2f(a2);
  return kv * w;
}

// ---------------- crf_kernel: f16 LDS tile, DPP reductions, fused softmax/CE + stats blocks
//                  + device-side finalization in the last-arriving block ----------------
__global__ __launch_bounds__(256, 6) void crf_kernel(
    const float* __restrict__ logit, const int* __restrict__ target,
    const float* __restrict__ image, const float* __restrict__ depth,
    const float* __restrict__ dst,
    float* __restrict__ g_bins, float* __restrict__ g_ce,
    float* __restrict__ rowBand, float* __restrict__ colBand,
    int* __restrict__ g_cnt, float* __restrict__ out) {
  __shared__ PixV  tile[TPIX];
  __shared__ float binsS[NBINS];
  __shared__ float redS[12];
  __shared__ int   lastFlag;

  int tx = threadIdx.x;
  int bid = blockIdx.x;
  int lane = tx & 63;

  if (bid >= NCRF) {           // ---- stats path: margin band sums of dst ----
    int k = bid - NCRF;
    float s = 0.f;
    if (k < 22) {
      int row = (k < 11) ? k : (234 + k);
      for (int t = tx; t < 2048; t += 256) {
        int b = t >> 9, j = t & 511;
        s += dst[(size_t)b*HW + row*W + j];
      }
    } else {
      int kc = k - 22;
      int col = (kc < 11) ? kc : (490 + kc);
      for (int t = tx; t < 1024; t += 256) {
        int b = t >> 8, i = t & 255;
        s += dst[(size_t)b*HW + i*W + col];
      }
    }
    s = wave_sum(s);
    if ((tx & 63) == 0) redS[tx >> 6] = s;
    __syncthreads();
    if (tx == 0) {
      float tot = redS[0] + redS[1] + redS[2] + redS[3];
      if (k < 22) unsafeAtomicAdd(&rowBand[k], tot);
      else        unsafeAtomicAdd(&colBand[k - 22], tot);
    }
  } else {                     // ---- crf path ----
    int bz = bid >> 8;
    int rem = bid & 255;
    int i0 = (rem >> 4) * TYR;
    int j0 = (rem & 15) * TX;

    const float* lg0 = logit + (size_t)bz*3*HW;
    const float* lg1 = lg0 + HW;
    const float* lg2 = lg0 + 2*HW;
    const float* im0 = image + (size_t)bz*3*HW;
    const float* im1 = im0 + HW;
    const float* im2 = im0 + 2*HW;
    const float* dep = depth + (size_t)bz*HW;
    const float* dsb = dst   + (size_t)bz*HW;
    const int*   tgb = target + (size_t)bz*HW;

    for (int s = tx; s < NBINS; s += 256) binsS[s] = 0.f;

    // --- staging: global -> LDS (f16 pack, rgb/d pre-scaled) with fused softmax; fused CE + sum(m) ---
    float v0 = 0.f, v1 = 0.f, v2 = 0.f;
    for (int s = tx; s < TPIX; s += 256) {
      int r = s / TCOLS, c = s - r*TCOLS;
      int gi = i0 + r, gj = j0 - 11 + c;
      PixV ph;
      if (gi < H && (unsigned)gj < (unsigned)W) {
        int q = gi*W + gj;
        float l0 = lg0[q], l1 = lg1[q], l2 = lg2[q];
        float mx = fmaxf(l0, fmaxf(l1, l2));
        float e0 = __builtin_amdgcn_exp2f((l0-mx)*LOG2E);
        float e1 = __builtin_amdgcn_exp2f((l1-mx)*LOG2E);
        float e2 = __builtin_amdgcn_exp2f((l2-mx)*LOG2E);
        float S = e0+e1+e2;
        float inv = 1.0f/S;
        float m = dsb[q];
        ph.rg  = pack2(im0[q]*KRGB, im1[q]*KRGB);
        ph.bd  = pack2(im2[q]*KRGB, dep[q]*KDEP);
        ph.y01 = pack2(e0*inv, e1*inv);
        ph.y2m = pack2(e2*inv, m);
        if (r < TYR && c >= 11 && c < 11+TX) {   // center pixel
          int t = tgb[q];
          float lt = (t==0) ? l0 : ((t==1) ? l1 : l2);
          float lce = mx + __logf(S) - lt;
          float t0 = lce * m;
          v0 += t0;
          v1 += lce - t0;
          v2 += m;
        }
      } else {
        ph.rg = ph.bd = pack2(1e30f, 1e30f);   // +inf sentinel -> kernel = 0
        ph.y01 = ph.y2m = pack2(0.f, 0.f);     // m = 0
      }
      tile[s] = ph;
    }
    __syncthreads();

    // --- main pair loop: thread owns 2 center rows; half-plane offsets (a>=1), both bins ---
    int txc = tx & 31, ty = tx >> 5;
    int crow = ty*2;
    int cidx = crow*TCOLS + txc + 11;
    PixV c0 = tile[cidx];
    PixV c1 = tile[cidx+TCOLS];
    h2 nc01_0 = -c0.y01;
    h2 nc01_1 = -c1.y01;
    h2 nc2z_0; nc2z_0.x = -c0.y2m.x; nc2z_0.y = (_Float16)0.f;
    h2 nc2z_1; nc2z_1.x = -c1.y2m.x; nc2z_1.y = (_Float16)0.f;
    float c0m = (float)c0.y2m.y;
    float c1m = (float)c1.y2m.y;

    #pragma unroll 1
    for (int bi = 0; bi < 22; ++bi) {
      int db = bi - ((bi < 11) ? 11 : 10);   // -11..-1, 1..11
      int nb = cidx + db;
      float lb = CIND * (float)(db*db);
      int bb = SPAN*KK + (db + SPAN);        // bin base; idx(+a,+db) = bb + a*KK, idx(-a,-db) = 528 - that
      PixV N0 = tile[nb+TCOLS];              // row crow+1
      float N0m = (float)N0.y2m.y;
      #pragma unroll
      for (int a = 1; a <= 11; ++a) {
        PixV N1 = tile[nb + (a+1)*TCOLS];
        float lind = fmaf((float)(a*a), CIND, lb);   // a const -> folds to add
        float cc0 = paircc(c0, N0, nc01_0, nc2z_0, lind);
        float cc1 = paircc(c1, N1, nc01_1, nc2z_1, lind);
        float N1m = (float)N1.y2m.y;
        float nd = fmaf(cc1, c1m, cc0*c0m);  // -> bin(+a,+db), center m
        float nr = fmaf(cc1, N1m, cc0*N0m);  // -> bin(-a,-db), neighbor m
        nd = dpp_sum(nd);
        nr = dpp_sum(nr);
        if (lane == 63) {
          int id = bb + a*KK;
          atomicAdd(&binsS[id], nd);
          atomicAdd(&binsS[528 - id], nr);
        }
        N0 = N1; N0m = N1m;
      }
    }
    __syncthreads();

    // --- flush bins + CE ---
    for (int s = tx; s < NBINS; s += 256) {
      float v = binsS[s];
      if (v != 0.f) unsafeAtomicAdd(&g_bins[s], v);
    }
    v0 = dpp_sum(v0); v1 = dpp_sum(v1); v2 = dpp_sum(v2);
    int wv = tx >> 6;
    if (lane == 63) { redS[wv] = v0; redS[4+wv] = v1; redS[8+wv] = v2; }
    __syncthreads();
    if (tx == 0) {
      unsafeAtomicAdd(&g_ce[0], redS[0]+redS[1]+redS[2]+redS[3]);
      unsafeAtomicAdd(&g_ce[1], redS[4]+redS[5]+redS[6]+redS[7]);
      unsafeAtomicAdd(&g_ce[2], redS[8]+redS[9]+redS[10]+redS[11]);
    }
  }

  // ---- completion counter: last-arriving block runs finalization ----
  if (tx == 0) {
    __threadfence();
    int old = atomicAdd(g_cnt, 1);
    lastFlag = (old == NBLK - 1);
  }
  __syncthreads();
  if (!lastFlag) return;
  __threadfence();

  // ---- finalization: analytic denominators via 2D prefix sum (inclusion-exclusion) ----
  // overlay scratch onto the (dead) pixel tile
  float* fbuf   = (float*)tile;
  float* corner = fbuf;            // [22][22]
  float* rowp   = fbuf + 484;      // [22][23] exclusive row prefixes
  float* Pp     = fbuf + 990;      // [23][23] exclusive 2D prefix
  float* TopP   = fbuf + 1519;     // [12]
  float* BotS   = fbuf + 1531;     // [12]
  float* LeftP  = fbuf + 1543;     // [12]
  float* RightS = fbuf + 1555;     // [12]
  float* redF   = fbuf + 1567;     // [4]
  float* rb     = fbuf + 1571;     // [22]
  float* cb     = fbuf + 1593;     // [22]

  if (tx < 22) { rb[tx] = agent_load(&rowBand[tx]); cb[tx] = agent_load(&colBand[tx]); }
  for (int t = tx; t < 484; t += 256) {
    int ri = t / 22, ci = t - ri*22;
    int row = (ri < 11) ? ri : (234 + ri);
    int col = (ci < 11) ? ci : (490 + ci);
    float s = 0.f;
    #pragma unroll
    for (int b = 0; b < 4; ++b) s += dst[(size_t)b*HW + row*W + col];
    corner[t] = s;
  }
  __syncthreads();

  if (tx < 22) {
    float p = 0.f; rowp[tx*23] = 0.f;
    for (int j = 0; j < 22; ++j) { p += corner[tx*22 + j]; rowp[tx*23 + j + 1] = p; }
  }
  else if (tx == 32) { float p=0.f; TopP[0]=0.f;   for (int k=1;k<12;++k){ p += rb[k-1];  TopP[k]=p; } }
  else if (tx == 33) { float p=0.f; BotS[0]=0.f;   for (int k=1;k<12;++k){ p += rb[22-k]; BotS[k]=p; } }
  else if (tx == 34) { float p=0.f; LeftP[0]=0.f;  for (int k=1;k<12;++k){ p += cb[k-1];  LeftP[k]=p; } }
  else if (tx == 35) { float p=0.f; RightS[0]=0.f; for (int k=1;k<12;++k){ p += cb[22-k]; RightS[k]=p; } }
  __syncthreads();

  if (tx < 23) {
    float p = 0.f; Pp[tx] = 0.f;
    for (int i = 0; i < 22; ++i) { p += rowp[i*23 + tx]; Pp[(i+1)*23 + tx] = p; }
  }
  __syncthreads();

  float S = agent_load(&g_ce[2]);   // sum of dst over everything
  float esum = 0.f;
  for (int od = tx; od < NBINS; od += 256) {
    int dxp = od / KK, dyp = od - dxp*KK;
    int dx = dxp - SPAN, dy = dyp - SPAN;
    if (dx != 0 && dy != 0) {
      int ax = (dx < 0) ? -dx : 0;
      int bx = (dx > 0) ?  dx : 0;
      int ay = (dy < 0) ? -dy : 0;
      int by = (dy > 0) ?  dy : 0;
      float TLv = Pp[ax*23 + ay];
      float TRv = Pp[ax*23 + 22] - Pp[ax*23 + 22 - by];
      float BLv = Pp[22*23 + ay] - Pp[(22-bx)*23 + ay];
      float BRv = Pp[22*23 + 22] - Pp[(22-bx)*23 + 22] - Pp[22*23 + 22 - by] + Pp[(22-bx)*23 + 22 - by];
      float den = S - TopP[ax] - BotS[bx] - LeftP[ay] - RightS[by]
                + TLv + TRv + BLv + BRv;
      esum += agent_load(&g_bins[od]) / den;
    }
  }
  esum = wave_sum(esum);
  int wv2 = tx >> 6;
  if (lane == 0) redF[wv2] = esum;
  __syncthreads();
  if (tx == 0) {
    float E = (redF[0]+redF[1]+redF[2]+redF[3]) / 529.0f;
    float count = S / NPIXF;
    float l1 = agent_load(&g_ce[0]) / NPIXF;
    float l2 = agent_load(&g_ce[1]) / NPIXF;
    out[0] = l1*(1.0f - count) + l2*count;
    out[1] = E;
  }
}

extern "C" void kernel_launch(void* const* d_in, const int* in_sizes, int n_in,
                              void* d_out, int out_size, void* d_ws, size_t ws_size,
                              hipStream_t stream) {
  const float* logit  = (const float*)d_in[0];
  const int*   target = (const int*)  d_in[1];
  const float* image  = (const float*)d_in[2];
  const float* depth  = (const float*)d_in[3];
  const float* dstm   = (const float*)d_in[4];
  float* out = (float*)d_out;

  float* ws      = (float*)d_ws;
  float* g_bins  = ws;             // 529
  float* g_ce    = ws + NBINS;     // 3  (sum lce*m, sum lce*(1-m), sum m)
  float* rowBand = ws + 532;       // 22
  float* colBand = ws + 554;       // 22
  int*   g_cnt   = (int*)(ws + 576);

  hipMemsetAsync(ws, 0, 577*sizeof(float), stream);
  crf_kernel<<<NBLK, 256, 0, stream>>>(logit, target, image, depth, dstm,
                                       g_bins, g_ce, rowBand, colBand, g_cnt, out);
}

// Round 6
// 207.798 us; speedup vs baseline: 1.1246x; 1.1246x over previous
//
#include <hip/hip_runtime.h>
#include <hip/hip_fp16.h>

#define H 256
#define W 512
#define HW (H*W)
#define NPIXF 524288.0f
#define SPAN 11
#define KK 23
#define NBINS (KK*KK)   // 529

#define LOG2E 1.4426950408889634f
#define CEXP  (-0.7213475204444817f)   // -0.5*log2(e)
#define CIND  (CEXP/36.0f)             // 1/SIG_XY^2
// sqrt(|CEXP|*100) and sqrt(|CEXP|*25): fold rgb/depth sigma scaling into staged f16 data
#define KRGB  8.4932180f
#define KDEP  4.2466090f

// tile geometry: center 32 cols x 32 rows per block, halo +11 rows below, +-11 cols
#define TX 32
#define TYR 32
#define TROWS 43          // TYR + 11
#define TCOLS 54          // TX + 22
#define TPIX (TROWS*TCOLS) // 2322

#define NCRF 512          // 8x16x4 crf blocks (32x32 tiles)
#define NSTAT 44

typedef _Float16 h2 __attribute__((ext_vector_type(2)));

struct alignas(16) PixV { h2 rg, bd, y01, y2m; };   // 16 B staged pixel (rgb,d pre-scaled)

__device__ __forceinline__ h2 pack2(float a, float b) {
  h2 r; r.x = (_Float16)a; r.y = (_Float16)b; return r;
}

// 64-lane sum on the VALU pipe (DPP). Total lands in lane 63.
__device__ __forceinline__ float dpp_sum(float x) {
  x += __int_as_float(__builtin_amdgcn_update_dpp(0, __float_as_int(x), 0x111, 0xf, 0xf, true)); // row_shr:1
  x += __int_as_float(__builtin_amdgcn_update_dpp(0, __float_as_int(x), 0x112, 0xf, 0xf, true)); // row_shr:2
  x += __int_as_float(__builtin_amdgcn_update_dpp(0, __float_as_int(x), 0x114, 0xf, 0xf, true)); // row_shr:4
  x += __int_as_float(__builtin_amdgcn_update_dpp(0, __float_as_int(x), 0x118, 0xf, 0xf, true)); // row_shr:8
  x += __int_as_float(__builtin_amdgcn_update_dpp(0, __float_as_int(x), 0x142, 0xa, 0xf, true)); // row_bcast:15
  x += __int_as_float(__builtin_amdgcn_update_dpp(0, __float_as_int(x), 0x143, 0xc, 0xf, true)); // row_bcast:31
  return x;
}

__device__ __forceinline__ float wave_sum(float x) {
  #pragma unroll
  for (int s = 1; s < 64; s <<= 1) x += __shfl_xor(x, s, 64);
  return x;
}

// pair compatibility: kv(a1,a2) * (1 - <yC, yN>), all f16-packed inputs
__device__ __forceinline__ float paircc(const PixV& C, const PixV& N,
                                        h2 nc01, h2 nc2z, float lind) {
  h2 drg = N.rg - C.rg;            // v_pk_add_f16 (neg)
  h2 dbd = N.bd - C.bd;
  float dbf = (float)dbd.x;
  float ddf = (float)dbd.y;
#if __has_builtin(__builtin_amdgcn_fdot2)
  float q  = __builtin_amdgcn_fdot2(drg, drg, dbf*dbf, false);   // dr^2+dg^2+db^2 (scaled)
  float a1 = lind - q;
  float w1 = __builtin_amdgcn_fdot2(N.y01, nc01, 1.0f, false);   // 1 - y0Y0 - y1Y1
  float w  = __builtin_amdgcn_fdot2(N.y2m, nc2z, w1, false);     // ... - y2Y2 (m lane masked by 0)
#else
  float dr = (float)drg.x, dg = (float)drg.y;
  float a1 = fmaf(-dr, dr, fmaf(-dg, dg, fmaf(-dbf, dbf, lind)));
  float ny0 = (float)N.y01.x, ny1 = (float)N.y01.y, ny2 = (float)N.y2m.x;
  float cy0 = (float)C.y01.x, cy1 = (float)C.y01.y, cy2 = (float)C.y2m.x;
  float w  = fmaf(-ny0, cy0, fmaf(-ny1, cy1, fmaf(-ny2, cy2, 1.0f)));
  (void)nc01; (void)nc2z;
#endif
  float a2 = -(ddf*ddf);
  float kv = __builtin_amdgcn_exp2f(a1) + __builtin_amdgcn_exp2f(a2);
  return kv * w;
}

// ---------------- crf_kernel: f16 LDS tile, 4 center rows/thread, DPP reductions,
//                  fused softmax/CE + stats blocks ----------------
__global__ __launch_bounds__(256, 4) void crf_kernel(
    const float* __restrict__ logit, const int* __restrict__ target,
    const float* __restrict__ image, const float* __restrict__ depth,
    const float* __restrict__ dst,
    float* __restrict__ g_bins, float* __restrict__ g_ce,
    float* __restrict__ rowBand, float* __restrict__ colBand) {
  __shared__ PixV  tile[TPIX];
  __shared__ float binsS[NBINS];
  __shared__ float redS[12];

  int tx = threadIdx.x;
  int bid = blockIdx.x;
  int lane = tx & 63;

  if (bid >= NCRF) {           // ---- stats path: margin band sums of dst ----
    int k = bid - NCRF;
    float s = 0.f;
    if (k < 22) {
      int row = (k < 11) ? k : (234 + k);
      for (int t = tx; t < 2048; t += 256) {
        int b = t >> 9, j = t & 511;
        s += dst[(size_t)b*HW + row*W + j];
      }
    } else {
      int kc = k - 22;
      int col = (kc < 11) ? kc : (490 + kc);
      for (int t = tx; t < 1024; t += 256) {
        int b = t >> 8, i = t & 255;
        s += dst[(size_t)b*HW + i*W + col];
      }
    }
    s = wave_sum(s);
    if ((tx & 63) == 0) redS[tx >> 6] = s;
    __syncthreads();
    if (tx == 0) {
      float tot = redS[0] + redS[1] + redS[2] + redS[3];
      if (k < 22) rowBand[k] = tot; else colBand[k - 22] = tot;
    }
    return;
  }

  int bz = bid >> 7;           // 128 blocks per batch (8 row-tiles x 16 col-tiles)
  int rem = bid & 127;
  int i0 = (rem >> 4) * TYR;
  int j0 = (rem & 15) * TX;

  const float* lg0 = logit + (size_t)bz*3*HW;
  const float* lg1 = lg0 + HW;
  const float* lg2 = lg0 + 2*HW;
  const float* im0 = image + (size_t)bz*3*HW;
  const float* im1 = im0 + HW;
  const float* im2 = im0 + 2*HW;
  const float* dep = depth + (size_t)bz*HW;
  const float* dsb = dst   + (size_t)bz*HW;
  const int*   tgb = target + (size_t)bz*HW;

  for (int s = tx; s < NBINS; s += 256) binsS[s] = 0.f;

  // --- staging: global -> LDS (f16 pack, rgb/d pre-scaled) with fused softmax; fused CE + sum(m) ---
  float v0 = 0.f, v1 = 0.f, v2 = 0.f;
  for (int s = tx; s < TPIX; s += 256) {
    int r = s / TCOLS, c = s - r*TCOLS;
    int gi = i0 + r, gj = j0 - 11 + c;
    PixV ph;
    if (gi < H && (unsigned)gj < (unsigned)W) {
      int q = gi*W + gj;
      float l0 = lg0[q], l1 = lg1[q], l2 = lg2[q];
      float mx = fmaxf(l0, fmaxf(l1, l2));
      float e0 = __builtin_amdgcn_exp2f((l0-mx)*LOG2E);
      float e1 = __builtin_amdgcn_exp2f((l1-mx)*LOG2E);
      float e2 = __builtin_amdgcn_exp2f((l2-mx)*LOG2E);
      float S = e0+e1+e2;
      float inv = 1.0f/S;
      float m = dsb[q];
      ph.rg  = pack2(im0[q]*KRGB, im1[q]*KRGB);
      ph.bd  = pack2(im2[q]*KRGB, dep[q]*KDEP);
      ph.y01 = pack2(e0*inv, e1*inv);
      ph.y2m = pack2(e2*inv, m);
      if (r < TYR && c >= 11 && c < 11+TX) {   // center pixel
        int t = tgb[q];
        float lt = (t==0) ? l0 : ((t==1) ? l1 : l2);
        float lce = mx + __logf(S) - lt;
        float t0 = lce * m;
        v0 += t0;
        v1 += lce - t0;
        v2 += m;
      }
    } else {
      ph.rg = ph.bd = pack2(1e30f, 1e30f);   // +inf sentinel -> kernel = 0
      ph.y01 = ph.y2m = pack2(0.f, 0.f);     // m = 0
    }
    tile[s] = ph;
  }
  __syncthreads();

  // --- main pair loop: thread owns 4 center rows; half-plane offsets (a>=1), both bins.
  //     One ds_read + one DPP-reduce pair per iteration covers 4 pixel-pairs. ---
  int txc = tx & 31, ty = tx >> 5;
  int crow = ty*4;
  int cidx = crow*TCOLS + txc + 11;
  PixV c0 = tile[cidx];
  PixV c1 = tile[cidx +   TCOLS];
  PixV c2 = tile[cidx + 2*TCOLS];
  PixV c3 = tile[cidx + 3*TCOLS];
  h2 nc01_0 = -c0.y01, nc01_1 = -c1.y01, nc01_2 = -c2.y01, nc01_3 = -c3.y01;
  h2 nc2z_0; nc2z_0.x = -c0.y2m.x; nc2z_0.y = (_Float16)0.f;
  h2 nc2z_1; nc2z_1.x = -c1.y2m.x; nc2z_1.y = (_Float16)0.f;
  h2 nc2z_2; nc2z_2.x = -c2.y2m.x; nc2z_2.y = (_Float16)0.f;
  h2 nc2z_3; nc2z_3.x = -c3.y2m.x; nc2z_3.y = (_Float16)0.f;
  float cm0 = (float)c0.y2m.y;
  float cm1 = (float)c1.y2m.y;
  float cm2 = (float)c2.y2m.y;
  float cm3 = (float)c3.y2m.y;

  #pragma unroll 1
  for (int bi = 0; bi < 22; ++bi) {
    int db = bi - ((bi < 11) ? 11 : 10);   // -11..-1, 1..11
    int nb = cidx + db;
    float lb = CIND * (float)(db*db);
    int bb = SPAN*KK + (db + SPAN);        // bin base; idx(+a,+db) = bb + a*KK, idx(-a,-db) = 528 - that
    // window: at iteration a, w0..w3 = rows crow+a .. crow+a+3 (w_k pairs with center k)
    PixV w0 = tile[nb +   TCOLS];
    PixV w1 = tile[nb + 2*TCOLS];
    PixV w2 = tile[nb + 3*TCOLS];
    float m0 = (float)w0.y2m.y;
    float m1 = (float)w1.y2m.y;
    float m2 = (float)w2.y2m.y;
    #pragma unroll
    for (int a = 1; a <= 11; ++a) {
      PixV w3 = tile[nb + (a+3)*TCOLS];
      float m3 = (float)w3.y2m.y;
      float lind = fmaf((float)(a*a), CIND, lb);   // a const -> folds to add
      float cc0 = paircc(c0, w0, nc01_0, nc2z_0, lind);
      float cc1 = paircc(c1, w1, nc01_1, nc2z_1, lind);
      float cc2 = paircc(c2, w2, nc01_2, nc2z_2, lind);
      float cc3 = paircc(c3, w3, nc01_3, nc2z_3, lind);
      float nd = fmaf(cc3, cm3, fmaf(cc2, cm2, fmaf(cc1, cm1, cc0*cm0)));  // bin(+a,+db), center m
      float nr = fmaf(cc3, m3,  fmaf(cc2, m2,  fmaf(cc1, m1,  cc0*m0)));  // bin(-a,-db), neighbor m
      nd = dpp_sum(nd);
      nr = dpp_sum(nr);
      if (lane == 63) {
        int id = bb + a*KK;
        atomicAdd(&binsS[id], nd);
        atomicAdd(&binsS[528 - id], nr);
      }
      w0 = w1; w1 = w2; w2 = w3;
      m0 = m1; m1 = m2; m2 = m3;
    }
  }
  __syncthreads();

  // --- flush bins + CE ---
  for (int s = tx; s < NBINS; s += 256) {
    float v = binsS[s];
    if (v != 0.f) unsafeAtomicAdd(&g_bins[s], v);
  }
  v0 = dpp_sum(v0); v1 = dpp_sum(v1); v2 = dpp_sum(v2);
  int wv = tx >> 6;
  if (lane == 63) { redS[wv] = v0; redS[4+wv] = v1; redS[8+wv] = v2; }
  __syncthreads();
  if (tx == 0) {
    unsafeAtomicAdd(&g_ce[0], redS[0]+redS[1]+redS[2]+redS[3]);
    unsafeAtomicAdd(&g_ce[1], redS[4]+redS[5]+redS[6]+redS[7]);
    unsafeAtomicAdd(&g_ce[2], redS[8]+redS[9]+redS[10]+redS[11]);
  }
}

// ---------------- fin_kernel: analytic denominators via 2D prefix sum (inclusion-exclusion) ----------------
__global__ __launch_bounds__(256) void fin_kernel(const float* __restrict__ g_bins,
                                                  const float* __restrict__ g_ce,
                                                  const float* __restrict__ rowBand,
                                                  const float* __restrict__ colBand,
                                                  const float* __restrict__ dst,
                                                  float* __restrict__ out) {
  __shared__ float corner[22][22];
  __shared__ float rowp[22][23];     // exclusive row prefixes of corner
  __shared__ float P[23][23];        // exclusive 2D prefix: P[i][j] = sum_{r<i,c<j} corner[r][c]
  __shared__ float rb[22], cb[22];
  __shared__ float TopP[12], BotS[12], LeftP[12], RightS[12];
  __shared__ float red[4];
  int tx = threadIdx.x;
  if (tx < 22) { rb[tx] = rowBand[tx]; cb[tx] = colBand[tx]; }
  for (int t = tx; t < 484; t += 256) {
    int ri = t / 22, ci = t - ri*22;
    int row = (ri < 11) ? ri : (234 + ri);
    int col = (ci < 11) ? ci : (490 + ci);
    float s = 0.f;
    #pragma unroll
    for (int b = 0; b < 4; ++b) s += dst[(size_t)b*HW + row*W + col];
    corner[ri][ci] = s;
  }
  __syncthreads();

  if (tx < 22) {
    float p = 0.f; rowp[tx][0] = 0.f;
    for (int j = 0; j < 22; ++j) { p += corner[tx][j]; rowp[tx][j+1] = p; }
  }
  else if (tx == 32) { float p=0.f; TopP[0]=0.f;   for (int k=1;k<12;++k){ p += rb[k-1];  TopP[k]=p; } }
  else if (tx == 33) { float p=0.f; BotS[0]=0.f;   for (int k=1;k<12;++k){ p += rb[22-k]; BotS[k]=p; } }
  else if (tx == 34) { float p=0.f; LeftP[0]=0.f;  for (int k=1;k<12;++k){ p += cb[k-1];  LeftP[k]=p; } }
  else if (tx == 35) { float p=0.f; RightS[0]=0.f; for (int k=1;k<12;++k){ p += cb[22-k]; RightS[k]=p; } }
  __syncthreads();

  if (tx < 23) {
    float p = 0.f; P[0][tx] = 0.f;
    for (int i = 0; i < 22; ++i) { p += rowp[i][tx]; P[i+1][tx] = p; }
  }
  __syncthreads();

  float S = g_ce[2];   // sum of dst over everything
  float esum = 0.f;
  for (int od = tx; od < NBINS; od += 256) {
    int dxp = od / KK, dyp = od - dxp*KK;
    int dx = dxp - SPAN, dy = dyp - SPAN;
    if (dx != 0 && dy != 0) {
      int ax = (dx < 0) ? -dx : 0;
      int bx = (dx > 0) ?  dx : 0;
      int ay = (dy < 0) ? -dy : 0;
      int by = (dy > 0) ?  dy : 0;
      float TLv = P[ax][ay];
      float TRv = P[ax][22] - P[ax][22-by];
      float BLv = P[22][ay] - P[22-bx][ay];
      float BRv = P[22][22] - P[22-bx][22] - P[22][22-by] + P[22-bx][22-by];
      float den = S - TopP[ax] - BotS[bx] - LeftP[ay] - RightS[by]
                + TLv + TRv + BLv + BRv;
      esum += g_bins[od] / den;
    }
  }
  esum = wave_sum(esum);
  int lane = tx & 63, wv = tx >> 6;
  if (lane == 0) red[wv] = esum;
  __syncthreads();
  if (tx == 0) {
    float E = (red[0]+red[1]+red[2]+red[3]) / 529.0f;
    float count = S / NPIXF;
    float l1 = g_ce[0] / NPIXF;
    float l2 = g_ce[1] / NPIXF;
    out[0] = l1*(1.0f - count) + l2*count;
    out[1] = E;
  }
}

extern "C" void kernel_launch(void* const* d_in, const int* in_sizes, int n_in,
                              void* d_out, int out_size, void* d_ws, size_t ws_size,
                              hipStream_t stream) {
  const float* logit  = (const float*)d_in[0];
  const int*   target = (const int*)  d_in[1];
  const float* image  = (const float*)d_in[2];
  const float* depth  = (const float*)d_in[3];
  const float* dstm   = (const float*)d_in[4];
  float* out = (float*)d_out;

  float* ws      = (float*)d_ws;
  float* g_bins  = ws;             // 529
  float* g_ce    = ws + NBINS;     // 3  (sum lce*m, sum lce*(1-m), sum m)
  float* rowBand = ws + 532;       // 22
  float* colBand = ws + 554;       // 22

  hipMemsetAsync(ws, 0, 532*sizeof(float), stream);
  crf_kernel<<<NCRF + NSTAT, 256, 0, stream>>>(logit, target, image, depth, dstm,
                                               g_bins, g_ce, rowBand, colBand);
  fin_kernel<<<1, 256, 0, stream>>>(g_bins, g_ce, rowBand, colBand, dstm, out);
}

// Round 9
// 195.962 us; speedup vs baseline: 1.1925x; 1.0604x over previous
//
#include <hip/hip_runtime.h>
#include <hip/hip_fp16.h>

#define H 256
#define W 512
#define HW (H*W)
#define NPIXF 524288.0f
#define SPAN 11
#define KK 23
#define NBINS (KK*KK)   // 529

#define LOG2E 1.4426950408889634f
#define CEXP  (-0.7213475204444817f)   // -0.5*log2(e)
#define CIND  (CEXP/36.0f)             // 1/SIG_XY^2
// sqrt(|CEXP|*100) and sqrt(|CEXP|*25): fold rgb/depth sigma scaling into staged f16 data
#define KRGB  8.4932180f
#define KDEP  4.2466090f

// tile geometry: center 32 cols x 32 rows per block, halo +11 rows below, +-11 cols
#define TX 32
#define TYR 32
#define TROWS 43          // TYR + 11
#define TCOLS 54          // TX + 22
#define TPIX (TROWS*TCOLS) // 2322

#define NTILE 512         // 32x32-center tiles: 4 batches x 8 rowtiles x 16 coltiles
#define NCRF (NTILE*2)    // 2 blocks per tile (db<0 half, db>0 half)
#define NSTAT 44

typedef _Float16 h2 __attribute__((ext_vector_type(2)));

struct alignas(16) PixV { h2 rg, bd, y01, y2m; };   // 16 B staged pixel (rgb,d pre-scaled)

__device__ __forceinline__ h2 pack2(float a, float b) {
  h2 r; r.x = (_Float16)a; r.y = (_Float16)b; return r;
}

// 64-lane sum on the VALU pipe (DPP). Total lands in lane 63.
__device__ __forceinline__ float dpp_sum(float x) {
  x += __int_as_float(__builtin_amdgcn_update_dpp(0, __float_as_int(x), 0x111, 0xf, 0xf, true)); // row_shr:1
  x += __int_as_float(__builtin_amdgcn_update_dpp(0, __float_as_int(x), 0x112, 0xf, 0xf, true)); // row_shr:2
  x += __int_as_float(__builtin_amdgcn_update_dpp(0, __float_as_int(x), 0x114, 0xf, 0xf, true)); // row_shr:4
  x += __int_as_float(__builtin_amdgcn_update_dpp(0, __float_as_int(x), 0x118, 0xf, 0xf, true)); // row_shr:8
  x += __int_as_float(__builtin_amdgcn_update_dpp(0, __float_as_int(x), 0x142, 0xa, 0xf, true)); // row_bcast:15
  x += __int_as_float(__builtin_amdgcn_update_dpp(0, __float_as_int(x), 0x143, 0xc, 0xf, true)); // row_bcast:31
  return x;
}

__device__ __forceinline__ float wave_sum(float x) {
  #pragma unroll
  for (int s = 1; s < 64; s <<= 1) x += __shfl_xor(x, s, 64);
  return x;
}

// pair compatibility: kv(a1,a2) * (1 - <yC, yN>), all f16-packed inputs
__device__ __forceinline__ float paircc(const PixV& C, const PixV& N,
                                        h2 nc01, h2 nc2z, float lind) {
  h2 drg = N.rg - C.rg;            // v_pk_add_f16 (neg)
  h2 dbd = N.bd - C.bd;
  float dbf = (float)dbd.x;
  float ddf = (float)dbd.y;
#if __has_builtin(__builtin_amdgcn_fdot2)
  float q  = __builtin_amdgcn_fdot2(drg, drg, dbf*dbf, false);   // dr^2+dg^2+db^2 (scaled)
  float a1 = lind - q;
  float w1 = __builtin_amdgcn_fdot2(N.y01, nc01, 1.0f, false);   // 1 - y0Y0 - y1Y1
  float w  = __builtin_amdgcn_fdot2(N.y2m, nc2z, w1, false);     // ... - y2Y2 (m lane masked by 0)
#else
  float dr = (float)drg.x, dg = (float)drg.y;
  float a1 = fmaf(-dr, dr, fmaf(-dg, dg, fmaf(-dbf, dbf, lind)));
  float ny0 = (float)N.y01.x, ny1 = (float)N.y01.y, ny2 = (float)N.y2m.x;
  float cy0 = (float)C.y01.x, cy1 = (float)C.y01.y, cy2 = (float)C.y2m.x;
  float w  = fmaf(-ny0, cy0, fmaf(-ny1, cy1, fmaf(-ny2, cy2, 1.0f)));
  (void)nc01; (void)nc2z;
#endif
  float a2 = -(ddf*ddf);
  float kv = __builtin_amdgcn_exp2f(a1) + __builtin_amdgcn_exp2f(a2);
  return kv * w;
}

// ---------------- crf_kernel: f16 LDS tile, 4 center rows/thread, db-halved blocks,
//                  DPP reductions, fused softmax/CE + stats blocks ----------------
__global__ __launch_bounds__(256, 4) void crf_kernel(
    const float* __restrict__ logit, const int* __restrict__ target,
    const float* __restrict__ image, const float* __restrict__ depth,
    const float* __restrict__ dst,
    float* __restrict__ g_bins, float* __restrict__ g_ce,
    float* __restrict__ rowBand, float* __restrict__ colBand) {
  __shared__ PixV  tile[TPIX];
  __shared__ float binsS[NBINS];
  __shared__ float redS[12];

  int tx = threadIdx.x;
  int bid = blockIdx.x;
  int lane = tx & 63;

  if (bid >= NCRF) {           // ---- stats path: margin band sums of dst ----
    int k = bid - NCRF;
    float s = 0.f;
    if (k < 22) {
      int row = (k < 11) ? k : (234 + k);
      for (int t = tx; t < 2048; t += 256) {
        int b = t >> 9, j = t & 511;
        s += dst[(size_t)b*HW + row*W + j];
      }
    } else {
      int kc = k - 22;
      int col = (kc < 11) ? kc : (490 + kc);
      for (int t = tx; t < 1024; t += 256) {
        int b = t >> 8, i = t & 255;
        s += dst[(size_t)b*HW + i*W + col];
      }
    }
    s = wave_sum(s);
    if ((tx & 63) == 0) redS[tx >> 6] = s;
    __syncthreads();
    if (tx == 0) {
      float tot = redS[0] + redS[1] + redS[2] + redS[3];
      if (k < 22) rowBand[k] = tot; else colBand[k - 22] = tot;
    }
    return;
  }

  int tileId = bid >> 1;       // 512 tiles
  int half   = bid & 1;        // 0: db=-11..-1, 1: db=+1..+11
  int bz = tileId >> 7;        // 128 tiles per batch (8 row-tiles x 16 col-tiles)
  int rem = tileId & 127;
  int i0 = (rem >> 4) * TYR;
  int j0 = (rem & 15) * TX;

  const float* lg0 = logit + (size_t)bz*3*HW;
  const float* lg1 = lg0 + HW;
  const float* lg2 = lg0 + 2*HW;
  const float* im0 = image + (size_t)bz*3*HW;
  const float* im1 = im0 + HW;
  const float* im2 = im0 + 2*HW;
  const float* dep = depth + (size_t)bz*HW;
  const float* dsb = dst   + (size_t)bz*HW;
  const int*   tgb = target + (size_t)bz*HW;

  for (int s = tx; s < NBINS; s += 256) binsS[s] = 0.f;

  // --- staging: global -> LDS (f16 pack, rgb/d pre-scaled) with fused softmax;
  //     CE + sum(m) only on half 0 (avoid double count) ---
  float v0 = 0.f, v1 = 0.f, v2 = 0.f;
  for (int s = tx; s < TPIX; s += 256) {
    int r = s / TCOLS, c = s - r*TCOLS;
    int gi = i0 + r, gj = j0 - 11 + c;
    PixV ph;
    if (gi < H && (unsigned)gj < (unsigned)W) {
      int q = gi*W + gj;
      float l0 = lg0[q], l1 = lg1[q], l2 = lg2[q];
      float mx = fmaxf(l0, fmaxf(l1, l2));
      float e0 = __builtin_amdgcn_exp2f((l0-mx)*LOG2E);
      float e1 = __builtin_amdgcn_exp2f((l1-mx)*LOG2E);
      float e2 = __builtin_amdgcn_exp2f((l2-mx)*LOG2E);
      float S = e0+e1+e2;
      float inv = 1.0f/S;
      float m = dsb[q];
      ph.rg  = pack2(im0[q]*KRGB, im1[q]*KRGB);
      ph.bd  = pack2(im2[q]*KRGB, dep[q]*KDEP);
      ph.y01 = pack2(e0*inv, e1*inv);
      ph.y2m = pack2(e2*inv, m);
      if (half == 0 && r < TYR && c >= 11 && c < 11+TX) {   // center pixel, once per tile
        int t = tgb[q];
        float lt = (t==0) ? l0 : ((t==1) ? l1 : l2);
        float lce = mx + __logf(S) - lt;
        float t0 = lce * m;
        v0 += t0;
        v1 += lce - t0;
        v2 += m;
      }
    } else {
      ph.rg = ph.bd = pack2(1e30f, 1e30f);   // +inf sentinel -> kernel = 0
      ph.y01 = ph.y2m = pack2(0.f, 0.f);     // m = 0
    }
    tile[s] = ph;
  }
  __syncthreads();

  // --- main pair loop: thread owns 4 center rows; this block's 11 db offsets; both bins.
  //     One ds_read + one DPP-reduce pair per iteration covers 4 pixel-pairs. ---
  int txc = tx & 31, ty = tx >> 5;
  int crow = ty*4;
  int cidx = crow*TCOLS + txc + 11;
  PixV c0 = tile[cidx];
  PixV c1 = tile[cidx +   TCOLS];
  PixV c2 = tile[cidx + 2*TCOLS];
  PixV c3 = tile[cidx + 3*TCOLS];
  h2 nc01_0 = -c0.y01, nc01_1 = -c1.y01, nc01_2 = -c2.y01, nc01_3 = -c3.y01;
  h2 nc2z_0; nc2z_0.x = -c0.y2m.x; nc2z_0.y = (_Float16)0.f;
  h2 nc2z_1; nc2z_1.x = -c1.y2m.x; nc2z_1.y = (_Float16)0.f;
  h2 nc2z_2; nc2z_2.x = -c2.y2m.x; nc2z_2.y = (_Float16)0.f;
  h2 nc2z_3; nc2z_3.x = -c3.y2m.x; nc2z_3.y = (_Float16)0.f;
  float cm0 = (float)c0.y2m.y;
  float cm1 = (float)c1.y2m.y;
  float cm2 = (float)c2.y2m.y;
  float cm3 = (float)c3.y2m.y;

  int biLo = half * 11;        // 0..10 or 11..21
  #pragma unroll 1
  for (int bi = biLo; bi < biLo + 11; ++bi) {
    int db = bi - ((bi < 11) ? 11 : 10);   // -11..-1 (half 0), 1..11 (half 1)
    int nb = cidx + db;
    float lb = CIND * (float)(db*db);
    int bb = SPAN*KK + (db + SPAN);        // bin base; idx(+a,+db) = bb + a*KK, idx(-a,-db) = 528 - that
    // window: at iteration a, w0..w3 = rows crow+a .. crow+a+3 (w_k pairs with center k)
    PixV w0 = tile[nb +   TCOLS];
    PixV w1 = tile[nb + 2*TCOLS];
    PixV w2 = tile[nb + 3*TCOLS];
    float m0 = (float)w0.y2m.y;
    float m1 = (float)w1.y2m.y;
    float m2 = (float)w2.y2m.y;
    #pragma unroll
    for (int a = 1; a <= 11; ++a) {
      PixV w3 = tile[nb + (a+3)*TCOLS];
      float m3 = (float)w3.y2m.y;
      float lind = fmaf((float)(a*a), CIND, lb);   // a const -> folds to add
      float cc0 = paircc(c0, w0, nc01_0, nc2z_0, lind);
      float cc1 = paircc(c1, w1, nc01_1, nc2z_1, lind);
      float cc2 = paircc(c2, w2, nc01_2, nc2z_2, lind);
      float cc3 = paircc(c3, w3, nc01_3, nc2z_3, lind);
      float nd = fmaf(cc3, cm3, fmaf(cc2, cm2, fmaf(cc1, cm1, cc0*cm0)));  // bin(+a,+db), center m
      float nr = fmaf(cc3, m3,  fmaf(cc2, m2,  fmaf(cc1, m1,  cc0*m0)));  // bin(-a,-db), neighbor m
      nd = dpp_sum(nd);
      nr = dpp_sum(nr);
      if (lane == 63) {
        int id = bb + a*KK;
        atomicAdd(&binsS[id], nd);
        atomicAdd(&binsS[528 - id], nr);
      }
      w0 = w1; w1 = w2; w2 = w3;
      m0 = m1; m1 = m2; m2 = m3;
    }
  }
  __syncthreads();

  // --- flush bins (only this half's 242 bins are nonzero) + CE (half 0) ---
  for (int s = tx; s < NBINS; s += 256) {
    float v = binsS[s];
    if (v != 0.f) unsafeAtomicAdd(&g_bins[s], v);
  }
  if (half == 0) {
    v0 = dpp_sum(v0); v1 = dpp_sum(v1); v2 = dpp_sum(v2);
    int wv = tx >> 6;
    if (lane == 63) { redS[wv] = v0; redS[4+wv] = v1; redS[8+wv] = v2; }
    __syncthreads();
    if (tx == 0) {
      unsafeAtomicAdd(&g_ce[0], redS[0]+redS[1]+redS[2]+redS[3]);
      unsafeAtomicAdd(&g_ce[1], redS[4]+redS[5]+redS[6]+redS[7]);
      unsafeAtomicAdd(&g_ce[2], redS[8]+redS[9]+redS[10]+redS[11]);
    }
  }
}

// ---------------- fin_kernel: analytic denominators via 2D prefix sum (inclusion-exclusion) ----------------
__global__ __launch_bounds__(256) void fin_kernel(const float* __restrict__ g_bins,
                                                  const float* __restrict__ g_ce,
                                                  const float* __restrict__ rowBand,
                                                  const float* __restrict__ colBand,
                                                  const float* __restrict__ dst,
                                                  float* __restrict__ out) {
  __shared__ float corner[22][22];
  __shared__ float rowp[22][23];     // exclusive row prefixes of corner
  __shared__ float P[23][23];        // exclusive 2D prefix: P[i][j] = sum_{r<i,c<j} corner[r][c]
  __shared__ float rb[22], cb[22];
  __shared__ float TopP[12], BotS[12], LeftP[12], RightS[12];
  __shared__ float red[4];
  int tx = threadIdx.x;
  if (tx < 22) { rb[tx] = rowBand[tx]; cb[tx] = colBand[tx]; }
  for (int t = tx; t < 484; t += 256) {
    int ri = t / 22, ci = t - ri*22;
    int row = (ri < 11) ? ri : (234 + ri);
    int col = (ci < 11) ? ci : (490 + ci);
    float s = 0.f;
    #pragma unroll
    for (int b = 0; b < 4; ++b) s += dst[(size_t)b*HW + row*W + col];
    corner[ri][ci] = s;
  }
  __syncthreads();

  if (tx < 22) {
    float p = 0.f; rowp[tx][0] = 0.f;
    for (int j = 0; j < 22; ++j) { p += corner[tx][j]; rowp[tx][j+1] = p; }
  }
  else if (tx == 32) { float p=0.f; TopP[0]=0.f;   for (int k=1;k<12;++k){ p += rb[k-1];  TopP[k]=p; } }
  else if (tx == 33) { float p=0.f; BotS[0]=0.f;   for (int k=1;k<12;++k){ p += rb[22-k]; BotS[k]=p; } }
  else if (tx == 34) { float p=0.f; LeftP[0]=0.f;  for (int k=1;k<12;++k){ p += cb[k-1];  LeftP[k]=p; } }
  else if (tx == 35) { float p=0.f; RightS[0]=0.f; for (int k=1;k<12;++k){ p += cb[22-k]; RightS[k]=p; } }
  __syncthreads();

  if (tx < 23) {
    float p = 0.f; P[0][tx] = 0.f;
    for (int i = 0; i < 22; ++i) { p += rowp[i][tx]; P[i+1][tx] = p; }
  }
  __syncthreads();

  float S = g_ce[2];   // sum of dst over everything
  float esum = 0.f;
  for (int od = tx; od < NBINS; od += 256) {
    int dxp = od / KK, dyp = od - dxp*KK;
    int dx = dxp - SPAN, dy = dyp - SPAN;
    if (dx != 0 && dy != 0) {
      int ax = (dx < 0) ? -dx : 0;
      int bx = (dx > 0) ?  dx : 0;
      int ay = (dy < 0) ? -dy : 0;
      int by = (dy > 0) ?  dy : 0;
      float TLv = P[ax][ay];
      float TRv = P[ax][22] - P[ax][22-by];
      float BLv = P[22][ay] - P[22-bx][ay];
      float BRv = P[22][22] - P[22-bx][22] - P[22][22-by] + P[22-bx][22-by];
      float den = S - TopP[ax] - BotS[bx] - LeftP[ay] - RightS[by]
                + TLv + TRv + BLv + BRv;
      esum += g_bins[od] / den;
    }
  }
  esum = wave_sum(esum);
  int lane = tx & 63, wv = tx >> 6;
  if (lane == 0) red[wv] = esum;
  __syncthreads();
  if (tx == 0) {
    float E = (red[0]+red[1]+red[2]+red[3]) / 529.0f;
    float count = S / NPIXF;
    float l1 = g_ce[0] / NPIXF;
    float l2 = g_ce[1] / NPIXF;
    out[0] = l1*(1.0f - count) + l2*count;
    out[1] = E;
  }
}

extern "C" void kernel_launch(void* const* d_in, const int* in_sizes, int n_in,
                              void* d_out, int out_size, void* d_ws, size_t ws_size,
                              hipStream_t stream) {
  const float* logit  = (const float*)d_in[0];
  const int*   target = (const int*)  d_in[1];
  const float* image  = (const float*)d_in[2];
  const float* depth  = (const float*)d_in[3];
  const float* dstm   = (const float*)d_in[4];
  float* out = (float*)d_out;

  float* ws      = (float*)d_ws;
  float* g_bins  = ws;             // 529
  float* g_ce    = ws + NBINS;     // 3  (sum lce*m, sum lce*(1-m), sum m)
  float* rowBand = ws + 532;       // 22
  float* colBand = ws + 554;       // 22

  hipMemsetAsync(ws, 0, 532*sizeof(float), stream);
  crf_kernel<<<NCRF + NSTAT, 256, 0, stream>>>(logit, target, image, depth, dstm,
                                               g_bins, g_ce, rowBand, colBand);
  fin_kernel<<<1, 256, 0, stream>>>(g_bins, g_ce, rowBand, colBand, dstm, out);
}

// Round 10
// 191.868 us; speedup vs baseline: 1.2179x; 1.0213x over previous
//
#include <hip/hip_runtime.h>
#include <hip/hip_fp16.h>

#define H 256
#define W 512
#define HW (H*W)
#define NPIXF 524288.0f
#define SPAN 11
#define KK 23
#define NBINS (KK*KK)   // 529

#define LOG2E 1.4426950408889634f
#define CEXP  (-0.7213475204444817f)   // -0.5*log2(e)
#define CIND  (CEXP/36.0f)             // 1/SIG_XY^2
// sqrt(|CEXP|*100) and sqrt(|CEXP|*25): fold rgb/depth sigma scaling into staged f16 data
#define KRGB  8.4932180f
#define KDEP  4.2466090f

// tile geometry: center 32 cols x 32 rows per block, halo +11 rows below,
// ONE-SIDED 11-col halo (db-split makes the other side unnecessary)
#define TX 32
#define TYR 32
#define TROWS 43          // TYR + 11
#define TCOLS 43          // TX + 11 (one-sided halo)
#define TPIX (TROWS*TCOLS) // 1849

#define NTILE 512         // 32x32-center tiles: 4 batches x 8 rowtiles x 16 coltiles
#define NCRF (NTILE*2)    // 2 blocks per tile (db<0 half, db>0 half)
#define NSTAT 44

typedef _Float16 h2 __attribute__((ext_vector_type(2)));

struct alignas(16) PixV { h2 rg, bd, y01, y2m; };   // 16 B staged pixel (rgb,d pre-scaled)

__device__ __forceinline__ h2 pack2(float a, float b) {
  h2 r; r.x = (_Float16)a; r.y = (_Float16)b; return r;
}

// 64-lane sum on the VALU pipe (DPP). Total lands in lane 63.
__device__ __forceinline__ float dpp_sum(float x) {
  x += __int_as_float(__builtin_amdgcn_update_dpp(0, __float_as_int(x), 0x111, 0xf, 0xf, true)); // row_shr:1
  x += __int_as_float(__builtin_amdgcn_update_dpp(0, __float_as_int(x), 0x112, 0xf, 0xf, true)); // row_shr:2
  x += __int_as_float(__builtin_amdgcn_update_dpp(0, __float_as_int(x), 0x114, 0xf, 0xf, true)); // row_shr:4
  x += __int_as_float(__builtin_amdgcn_update_dpp(0, __float_as_int(x), 0x118, 0xf, 0xf, true)); // row_shr:8
  x += __int_as_float(__builtin_amdgcn_update_dpp(0, __float_as_int(x), 0x142, 0xa, 0xf, true)); // row_bcast:15
  x += __int_as_float(__builtin_amdgcn_update_dpp(0, __float_as_int(x), 0x143, 0xc, 0xf, true)); // row_bcast:31
  return x;
}

__device__ __forceinline__ float wave_sum(float x) {
  #pragma unroll
  for (int s = 1; s < 64; s <<= 1) x += __shfl_xor(x, s, 64);
  return x;
}

// pair compatibility: kv(a1,a2) * (1 - <yC, yN>), all f16-packed inputs
__device__ __forceinline__ float paircc(const PixV& C, const PixV& N,
                                        h2 nc01, h2 nc2z, float lind) {
  h2 drg = N.rg - C.rg;            // v_pk_add_f16 (neg)
  h2 dbd = N.bd - C.bd;
  float dbf = (float)dbd.x;
  float ddf = (float)dbd.y;
#if __has_builtin(__builtin_amdgcn_fdot2)
  float q  = __builtin_amdgcn_fdot2(drg, drg, dbf*dbf, false);   // dr^2+dg^2+db^2 (scaled)
  float a1 = lind - q;
  float w1 = __builtin_amdgcn_fdot2(N.y01, nc01, 1.0f, false);   // 1 - y0Y0 - y1Y1
  float w  = __builtin_amdgcn_fdot2(N.y2m, nc2z, w1, false);     // ... - y2Y2 (m lane masked by 0)
#else
  float dr = (float)drg.x, dg = (float)drg.y;
  float a1 = fmaf(-dr, dr, fmaf(-dg, dg, fmaf(-dbf, dbf, lind)));
  float ny0 = (float)N.y01.x, ny1 = (float)N.y01.y, ny2 = (float)N.y2m.x;
  float cy0 = (float)C.y01.x, cy1 = (float)C.y01.y, cy2 = (float)C.y2m.x;
  float w  = fmaf(-ny0, cy0, fmaf(-ny1, cy1, fmaf(-ny2, cy2, 1.0f)));
  (void)nc01; (void)nc2z;
#endif
  float a2 = -(ddf*ddf);
  float kv = __builtin_amdgcn_exp2f(a1) + __builtin_amdgcn_exp2f(a2);
  return kv * w;
}

// ---------------- crf_kernel: f16 LDS tile (one-sided halo), 4 center rows/thread,
//                  db-halved blocks, DPP reductions, fused softmax/CE + stats blocks ----------------
__global__ __launch_bounds__(256, 5) void crf_kernel(
    const float* __restrict__ logit, const int* __restrict__ target,
    const float* __restrict__ image, const float* __restrict__ depth,
    const float* __restrict__ dst,
    float* __restrict__ g_bins, float* __restrict__ g_ce,
    float* __restrict__ rowBand, float* __restrict__ colBand) {
  __shared__ PixV  tile[TPIX];
  __shared__ float binsS[NBINS];
  __shared__ float redS[12];

  int tx = threadIdx.x;
  int bid = blockIdx.x;
  int lane = tx & 63;

  if (bid >= NCRF) {           // ---- stats path: margin band sums of dst ----
    int k = bid - NCRF;
    float s = 0.f;
    if (k < 22) {
      int row = (k < 11) ? k : (234 + k);
      for (int t = tx; t < 2048; t += 256) {
        int b = t >> 9, j = t & 511;
        s += dst[(size_t)b*HW + row*W + j];
      }
    } else {
      int kc = k - 22;
      int col = (kc < 11) ? kc : (490 + kc);
      for (int t = tx; t < 1024; t += 256) {
        int b = t >> 8, i = t & 255;
        s += dst[(size_t)b*HW + i*W + col];
      }
    }
    s = wave_sum(s);
    if ((tx & 63) == 0) redS[tx >> 6] = s;
    __syncthreads();
    if (tx == 0) {
      float tot = redS[0] + redS[1] + redS[2] + redS[3];
      if (k < 22) rowBand[k] = tot; else colBand[k - 22] = tot;
    }
    return;
  }

  int tileId = bid >> 1;       // 512 tiles
  int half   = bid & 1;        // 0: db=-11..-1, 1: db=+1..+11
  int bz = tileId >> 7;        // 128 tiles per batch (8 row-tiles x 16 col-tiles)
  int rem = tileId & 127;
  int i0 = (rem >> 4) * TYR;
  int j0 = (rem & 15) * TX;
  int co = half ? 0 : 11;      // center col offset inside tile
  int cbase = j0 - co;         // global col of tile col 0

  const float* lg0 = logit + (size_t)bz*3*HW;
  const float* lg1 = lg0 + HW;
  const float* lg2 = lg0 + 2*HW;
  const float* im0 = image + (size_t)bz*3*HW;
  const float* im1 = im0 + HW;
  const float* im2 = im0 + 2*HW;
  const float* dep = depth + (size_t)bz*HW;
  const float* dsb = dst   + (size_t)bz*HW;
  const int*   tgb = target + (size_t)bz*HW;

  for (int s = tx; s < NBINS; s += 256) binsS[s] = 0.f;

  // --- staging: global -> LDS (f16 pack, rgb/d pre-scaled) with fused softmax;
  //     CE + sum(m) only on half 0 (avoid double count) ---
  float v0 = 0.f, v1 = 0.f, v2 = 0.f;
  for (int s = tx; s < TPIX; s += 256) {
    int r = s / TCOLS, c = s - r*TCOLS;
    int gi = i0 + r, gj = cbase + c;
    PixV ph;
    if (gi < H && (unsigned)gj < (unsigned)W) {
      int q = gi*W + gj;
      float l0 = lg0[q], l1 = lg1[q], l2 = lg2[q];
      float mx = fmaxf(l0, fmaxf(l1, l2));
      float e0 = __builtin_amdgcn_exp2f((l0-mx)*LOG2E);
      float e1 = __builtin_amdgcn_exp2f((l1-mx)*LOG2E);
      float e2 = __builtin_amdgcn_exp2f((l2-mx)*LOG2E);
      float S = e0+e1+e2;
      float inv = 1.0f/S;
      float m = dsb[q];
      ph.rg  = pack2(im0[q]*KRGB, im1[q]*KRGB);
      ph.bd  = pack2(im2[q]*KRGB, dep[q]*KDEP);
      ph.y01 = pack2(e0*inv, e1*inv);
      ph.y2m = pack2(e2*inv, m);
      if (half == 0 && r < TYR && c >= co && c < co+TX) {   // center pixel, once per tile
        int t = tgb[q];
        float lt = (t==0) ? l0 : ((t==1) ? l1 : l2);
        float lce = mx + __logf(S) - lt;
        float t0 = lce * m;
        v0 += t0;
        v1 += lce - t0;
        v2 += m;
      }
    } else {
      ph.rg = ph.bd = pack2(1e30f, 1e30f);   // +inf sentinel -> kernel = 0
      ph.y01 = ph.y2m = pack2(0.f, 0.f);     // m = 0
    }
    tile[s] = ph;
  }
  __syncthreads();

  // --- main pair loop: thread owns 4 center rows; this block's 11 db offsets; both bins.
  //     One ds_read + one DPP-reduce pair per iteration covers 4 pixel-pairs. ---
  int txc = tx & 31, ty = tx >> 5;
  int crow = ty*4;
  int cidx = crow*TCOLS + txc + co;
  PixV c0 = tile[cidx];
  PixV c1 = tile[cidx +   TCOLS];
  PixV c2 = tile[cidx + 2*TCOLS];
  PixV c3 = tile[cidx + 3*TCOLS];
  h2 nc01_0 = -c0.y01, nc01_1 = -c1.y01, nc01_2 = -c2.y01, nc01_3 = -c3.y01;
  h2 nc2z_0; nc2z_0.x = -c0.y2m.x; nc2z_0.y = (_Float16)0.f;
  h2 nc2z_1; nc2z_1.x = -c1.y2m.x; nc2z_1.y = (_Float16)0.f;
  h2 nc2z_2; nc2z_2.x = -c2.y2m.x; nc2z_2.y = (_Float16)0.f;
  h2 nc2z_3; nc2z_3.x = -c3.y2m.x; nc2z_3.y = (_Float16)0.f;
  float cm0 = (float)c0.y2m.y;
  float cm1 = (float)c1.y2m.y;
  float cm2 = (float)c2.y2m.y;
  float cm3 = (float)c3.y2m.y;

  int biLo = half * 11;        // 0..10 or 11..21
  #pragma unroll 1
  for (int bi = biLo; bi < biLo + 11; ++bi) {
    int db = bi - ((bi < 11) ? 11 : 10);   // -11..-1 (half 0), 1..11 (half 1)
    int nb = cidx + db;
    float lb = CIND * (float)(db*db);
    int bb = SPAN*KK + (db + SPAN);        // bin base; idx(+a,+db) = bb + a*KK, idx(-a,-db) = 528 - that
    // window: at iteration a, w0..w3 = rows crow+a .. crow+a+3 (w_k pairs with center k)
    PixV w0 = tile[nb +   TCOLS];
    PixV w1 = tile[nb + 2*TCOLS];
    PixV w2 = tile[nb + 3*TCOLS];
    float m0 = (float)w0.y2m.y;
    float m1 = (float)w1.y2m.y;
    float m2 = (float)w2.y2m.y;
    #pragma unroll
    for (int a = 1; a <= 11; ++a) {
      PixV w3 = tile[nb + (a+3)*TCOLS];
      float m3 = (float)w3.y2m.y;
      float lind = fmaf((float)(a*a), CIND, lb);   // a const -> folds to add
      float cc0 = paircc(c0, w0, nc01_0, nc2z_0, lind);
      float cc1 = paircc(c1, w1, nc01_1, nc2z_1, lind);
      float cc2 = paircc(c2, w2, nc01_2, nc2z_2, lind);
      float cc3 = paircc(c3, w3, nc01_3, nc2z_3, lind);
      float nd = fmaf(cc3, cm3, fmaf(cc2, cm2, fmaf(cc1, cm1, cc0*cm0)));  // bin(+a,+db), center m
      float nr = fmaf(cc3, m3,  fmaf(cc2, m2,  fmaf(cc1, m1,  cc0*m0)));  // bin(-a,-db), neighbor m
      nd = dpp_sum(nd);
      nr = dpp_sum(nr);
      if (lane == 63) {
        int id = bb + a*KK;
        atomicAdd(&binsS[id], nd);
        atomicAdd(&binsS[528 - id], nr);
      }
      w0 = w1; w1 = w2; w2 = w3;
      m0 = m1; m1 = m2; m2 = m3;
    }
  }
  __syncthreads();

  // --- flush bins (only this half's 242 bins are nonzero) + CE (half 0) ---
  for (int s = tx; s < NBINS; s += 256) {
    float v = binsS[s];
    if (v != 0.f) unsafeAtomicAdd(&g_bins[s], v);
  }
  if (half == 0) {
    v0 = dpp_sum(v0); v1 = dpp_sum(v1); v2 = dpp_sum(v2);
    int wv = tx >> 6;
    if (lane == 63) { redS[wv] = v0; redS[4+wv] = v1; redS[8+wv] = v2; }
    __syncthreads();
    if (tx == 0) {
      unsafeAtomicAdd(&g_ce[0], redS[0]+redS[1]+redS[2]+redS[3]);
      unsafeAtomicAdd(&g_ce[1], redS[4]+redS[5]+redS[6]+redS[7]);
      unsafeAtomicAdd(&g_ce[2], redS[8]+redS[9]+redS[10]+redS[11]);
    }
  }
}

// ---------------- fin_kernel: analytic denominators via 2D prefix sum (inclusion-exclusion) ----------------
__global__ __launch_bounds__(256) void fin_kernel(const float* __restrict__ g_bins,
                                                  const float* __restrict__ g_ce,
                                                  const float* __restrict__ rowBand,
                                                  const float* __restrict__ colBand,
                                                  const float* __restrict__ dst,
                                                  float* __restrict__ out) {
  __shared__ float corner[22][22];
  __shared__ float rowp[22][23];     // exclusive row prefixes of corner
  __shared__ float P[23][23];        // exclusive 2D prefix: P[i][j] = sum_{r<i,c<j} corner[r][c]
  __shared__ float rb[22], cb[22];
  __shared__ float TopP[12], BotS[12], LeftP[12], RightS[12];
  __shared__ float red[4];
  int tx = threadIdx.x;
  if (tx < 22) { rb[tx] = rowBand[tx]; cb[tx] = colBand[tx]; }
  for (int t = tx; t < 484; t += 256) {
    int ri = t / 22, ci = t - ri*22;
    int row = (ri < 11) ? ri : (234 + ri);
    int col = (ci < 11) ? ci : (490 + ci);
    float s = 0.f;
    #pragma unroll
    for (int b = 0; b < 4; ++b) s += dst[(size_t)b*HW + row*W + col];
    corner[ri][ci] = s;
  }
  __syncthreads();

  if (tx < 22) {
    float p = 0.f; rowp[tx][0] = 0.f;
    for (int j = 0; j < 22; ++j) { p += corner[tx][j]; rowp[tx][j+1] = p; }
  }
  else if (tx == 32) { float p=0.f; TopP[0]=0.f;   for (int k=1;k<12;++k){ p += rb[k-1];  TopP[k]=p; } }
  else if (tx == 33) { float p=0.f; BotS[0]=0.f;   for (int k=1;k<12;++k){ p += rb[22-k]; BotS[k]=p; } }
  else if (tx == 34) { float p=0.f; LeftP[0]=0.f;  for (int k=1;k<12;++k){ p += cb[k-1];  LeftP[k]=p; } }
  else if (tx == 35) { float p=0.f; RightS[0]=0.f; for (int k=1;k<12;++k){ p += cb[22-k]; RightS[k]=p; } }
  __syncthreads();

  if (tx < 23) {
    float p = 0.f; P[0][tx] = 0.f;
    for (int i = 0; i < 22; ++i) { p += rowp[i][tx]; P[i+1][tx] = p; }
  }
  __syncthreads();

  float S = g_ce[2];   // sum of dst over everything
  float esum = 0.f;
  for (int od = tx; od < NBINS; od += 256) {
    int dxp = od / KK, dyp = od - dxp*KK;
    int dx = dxp - SPAN, dy = dyp - SPAN;
    if (dx != 0 && dy != 0) {
      int ax = (dx < 0) ? -dx : 0;
      int bx = (dx > 0) ?  dx : 0;
      int ay = (dy < 0) ? -dy : 0;
      int by = (dy > 0) ?  dy : 0;
      float TLv = P[ax][ay];
      float TRv = P[ax][22] - P[ax][22-by];
      float BLv = P[22][ay] - P[22-bx][ay];
      float BRv = P[22][22] - P[22-bx][22] - P[22][22-by] + P[22-bx][22-by];
      float den = S - TopP[ax] - BotS[bx] - LeftP[ay] - RightS[by]
                + TLv + TRv + BLv + BRv;
      esum += g_bins[od] / den;
    }
  }
  esum = wave_sum(esum);
  int lane = tx & 63, wv = tx >> 6;
  if (lane == 0) red[wv] = esum;
  __syncthreads();
  if (tx == 0) {
    float E = (red[0]+red[1]+red[2]+red[3]) / 529.0f;
    float count = S / NPIXF;
    float l1 = g_ce[0] / NPIXF;
    float l2 = g_ce[1] / NPIXF;
    out[0] = l1*(1.0f - count) + l2*count;
    out[1] = E;
  }
}

extern "C" void kernel_launch(void* const* d_in, const int* in_sizes, int n_in,
                              void* d_out, int out_size, void* d_ws, size_t ws_size,
                              hipStream_t stream) {
  const float* logit  = (const float*)d_in[0];
  const int*   target = (const int*)  d_in[1];
  const float* image  = (const float*)d_in[2];
  const float* depth  = (const float*)d_in[3];
  const float* dstm   = (const float*)d_in[4];
  float* out = (float*)d_out;

  float* ws      = (float*)d_ws;
  float* g_bins  = ws;             // 529
  float* g_ce    = ws + NBINS;     // 3  (sum lce*m, sum lce*(1-m), sum m)
  float* rowBand = ws + 532;       // 22
  float* colBand = ws + 554;       // 22

  hipMemsetAsync(ws, 0, 532*sizeof(float), stream);
  crf_kernel<<<NCRF + NSTAT, 256, 0, stream>>>(logit, target, image, depth, dstm,
                                               g_bins, g_ce, rowBand, colBand);
  fin_kernel<<<1, 256, 0, stream>>>(g_bins, g_ce, rowBand, colBand, dstm, out);
}